// Round 10
// baseline (244.750 us; speedup 1.0000x reference)
//
#include <hip/hip_runtime.h>

// MMSE-PIC detector: B=32768, M=16, S=8, QAM16 Gray, 2 iterations.
// Round 10 = round 9 + static-LDS pad to unpin the register allocator.
// LLVM sets the VGPR budget from compile-time LDS-derived occupancy
// (8704B -> 16wg/CU -> 8 waves/EU -> 64 VGPRs, spilling ~3KB/wave; attrs
// couldn't override it in R5/R9). Padding static LDS to ~15.9KB drops the
// target to 10 blocks/CU = 5 waves/EU -> budget ~102 VGPRs -> no spills.
// 20 waves/CU is still >= the ~14-wave issue saturation point (R3 data).

#define EPS_F 1e-4f
#define INV_SQRT10 0.31622776601683794f
#define WSYNC() __builtin_amdgcn_wave_barrier()

typedef float v2f __attribute__((ext_vector_type(2)));

__device__ __forceinline__ float rcpf(float x) { return __builtin_amdgcn_rcpf(x); }
__device__ __forceinline__ float rsqf(float x) { return __builtin_amdgcn_rsqf(x); }
__device__ __forceinline__ float rdlane(float v, int l) {
    return __uint_as_float(__builtin_amdgcn_readlane(__float_as_uint(v), l));
}
template<int OFF>
__device__ __forceinline__ float swzf(float v) {
    return __uint_as_float(__builtin_amdgcn_ds_swizzle(__float_as_uint(v), OFF));
}
template<int CTRL>
__device__ __forceinline__ float dppf(float v) {
    return __int_as_float(__builtin_amdgcn_mov_dpp(__float_as_int(v), CTRL, 0xF, 0xF, true));
}
#define DPP_X1 0xB1   // quad_perm [1,0,3,2]  : lane ^ 1
#define DPP_X2 0x4E   // quad_perm [2,3,0,1]  : lane ^ 2
#define DPP_M8 0x141  // row_half_mirror      : lane ^ 7 within groups of 8
#define SWX4   0x101F // ds_swizzle           : lane ^ 4

__device__ __forceinline__ float pt_re(int p) {
    return (1.0f - 2.0f * (float)((p >> 3) & 1)) * (1.0f + 2.0f * (float)((p >> 1) & 1)) * INV_SQRT10;
}
__device__ __forceinline__ float pt_im(int p) {
    return (1.0f - 2.0f * (float)((p >> 2) & 1)) * (1.0f + 2.0f * (float)(p & 1)) * INV_SQRT10;
}

__global__ __launch_bounds__(128) __attribute__((amdgpu_waves_per_eu(4, 6)))
void mmse_pic_kernel(const float* __restrict__ y_re, const float* __restrict__ y_im,
                     const float* __restrict__ h_re, const float* __restrict__ h_im,
                     const float* __restrict__ prior,
                     const float* __restrict__ s_re, const float* __restrict__ s_im,
                     float* __restrict__ out)
{
    const int lane = threadIdx.x & 63;
    const int w    = threadIdx.x >> 6;            // wave id in block = sub-batch
    const int b    = blockIdx.x * 2 + w;
    const size_t bs = (size_t)b;

    // cols: 0-15 = S, 16-23 = h, 24 = y, 25-27 pad (sloppy-write landing zone)
    __shared__ __align__(16) v2f Sc[2][16][28];
    __shared__ v2f   xc_[2][8];
    __shared__ v2f   ymc_[2][8];
    __shared__ float vx_[2][8], ne_[2][8];
    __shared__ float lsig[2][64];
    __shared__ float llrD_[2][8][4];
    // Occupancy-control pad: never touched at runtime (blockIdx.x is never
    // negative as signed int), but the compiler cannot prove that, so the
    // allocation stays -> compile-time LDS ~15.9KB -> 5 waves/EU VGPR budget.
    __shared__ float ldspad[1880];

    // ---- load (vectorized, interleave re/im into float2) ----
    {
        const float4* pr4 = (const float4*)(s_re + bs * 256);
        const float4* pi4 = (const float4*)(s_im + bs * 256);
        float4 vr = pr4[lane], vi = pi4[lane];
        int r = lane >> 2, c0 = (lane & 3) << 2;
        Sc[w][r][c0+0] = (v2f){vr.x, vi.x};
        Sc[w][r][c0+1] = (v2f){vr.y, vi.y};
        Sc[w][r][c0+2] = (v2f){vr.z, vi.z};
        Sc[w][r][c0+3] = (v2f){vr.w, vi.w};
        if (lane < 32) {
            const float4* hr4 = (const float4*)(h_re + bs * 128);
            const float4* hi4 = (const float4*)(h_im + bs * 128);
            float4 hr = hr4[lane], hi = hi4[lane];
            int row = lane >> 1, col = 16 + ((lane & 1) << 2);
            Sc[w][row][col+0] = (v2f){hr.x, hi.x};
            Sc[w][row][col+1] = (v2f){hr.y, hi.y};
            Sc[w][row][col+2] = (v2f){hr.z, hi.z};
            Sc[w][row][col+3] = (v2f){hr.w, hi.w};
        }
        if (lane < 16) Sc[w][lane][24] = (v2f){y_re[bs*16+lane], y_im[bs*16+lane]};
        if (lane < 32) ((float*)llrD_[w])[lane] = prior[bs*32 + lane];
        if ((int)blockIdx.x < 0) ldspad[threadIdx.x] = vr.x;   // keeps pad alive, never runs
    }
    WSYNC();

    // ---- forward-only unnormalized elimination on [S | h y], column-pair b128 ----
    {
        const int r4 = lane >> 4;
        int jpr = lane & 15;
        const int jp = (jpr > 13) ? 13 : jpr;     // pairs 14,15 -> pad pair 13
        #pragma unroll
        for (int k = 0; k < 15; ++k) {
            float invd = rcpf(Sc[w][k][k].x);
            float4 rk = *(const float4*)&Sc[w][k][2*jp];
            const int p0 = k >> 2;
            #pragma unroll
            for (int p = 0; p < 4; ++p) {
                if (p < p0) continue;             // rows all finalized: skip
                int i = (p << 2) + r4;
                v2f aik = Sc[w][i][k];
                float mr = aik.x * invd, mi = aik.y * invd;
                if (p == p0) {                    // boundary block: protect rows i<=k
                    bool dead = (i <= k);
                    mr = dead ? 0.f : mr;
                    mi = dead ? 0.f : mi;
                }
                float4 a = *(float4*)&Sc[w][i][2*jp];
                a.x -= mr*rk.x - mi*rk.y;
                a.y -= mr*rk.y + mi*rk.x;
                a.z -= mr*rk.z - mi*rk.w;
                a.w -= mr*rk.w + mi*rk.z;
                *(float4*)&Sc[w][i][2*jp] = a;
            }
            WSYNC();
        }
    }
    // ---- scale RHS rows by rsqrt(d_m): W = D^-1/2 L^-1 [h|y] (= whitened) ----
    {
        int r2 = lane >> 2, c = lane & 3;
        float irs = rsqf(Sc[w][r2][r2].x);
        v2f v0 = Sc[w][r2][16 + c];
        Sc[w][r2][16 + c] = (v2f){v0.x*irs, v0.y*irs};
        v2f v1 = Sc[w][r2][20 + c];
        Sc[w][r2][20 + c] = (v2f){v1.x*irs, v1.y*irs};
        if (c == 0) {
            v2f v2 = Sc[w][r2][24];
            Sc[w][r2][24] = (v2f){v2.x*irs, v2.y*irs};
        }
    }
    WSYNC();

    // ---- Gram g[i][j] = (Wh^H Wh)[i][j] (1 entry/lane), y_mf = Wh^H Wy ----
    const int s = lane >> 3, u = lane & 7;
    float g_re = 0.f, g_im = 0.f, ym_r = 0.f, ym_i = 0.f;
    #pragma unroll
    for (int m = 0; m < 16; ++m) {
        v2f a  = Sc[w][m][16 + s];
        v2f x  = Sc[w][m][16 + u];
        v2f xy = Sc[w][m][24];
        g_re += a.x*x.x + a.y*x.y;      // conj(a)*x
        g_im += a.x*x.y - a.y*x.x;
        ym_r += a.x*xy.x + a.y*xy.y;
        ym_i += a.x*xy.y - a.y*xy.x;
    }
    if (u == 0) ymc_[w][s] = (v2f){ym_r, ym_i};
    WSYNC();

    const float pr = pt_re(u), pi2 = pt_im(u), pe = pr*pr + pi2*pi2;  // pt(u+8) = (-pr, pi2)
    float llr_a_reg = 0.f;

    for (int it = 0; it < 2; ++it) {
        // log-sigmoid table: one distinct value per lane
        {
            int ts = lane >> 3, tk = (lane >> 1) & 3, sg = lane & 1;
            float v = llrD_[w][ts][tk];
            float x = sg ? v : -v;
            lsig[w][lane] = fminf(x, 0.f) - __logf(1.0f + __expf(-fabsf(x)));
        }
        if (lane < 32) llr_a_reg = ((float*)llrD_[w])[lane];
        WSYNC();
        // symbol logits for p=u (l0) and p=u+8 (l1), in registers
        int base = s << 3;
        float lc = lsig[w][base | 2 | ((u >> 2) & 1)]
                 + lsig[w][base | 4 | ((u >> 1) & 1)]
                 + lsig[w][base | 6 | (u & 1)];
        float l0 = lc + lsig[w][base];
        float l1 = lc + lsig[w][base | 1];
        // moments: DPP-butterfly over the 8 lanes of stream s
        {
            float mx = fmaxf(l0, l1);
            mx = fmaxf(mx, dppf<DPP_X1>(mx));
            mx = fmaxf(mx, dppf<DPP_X2>(mx));
            mx = fmaxf(mx, dppf<DPP_M8>(mx));
            float w0 = __expf(l0 - mx), w1 = __expf(l1 - mx);
            float a = w0 + w1, dw = w0 - w1;
            float se = a, mr = dw * pr, mi = a * pi2, e2 = a * pe;
            se += dppf<DPP_X1>(se); mr += dppf<DPP_X1>(mr); mi += dppf<DPP_X1>(mi); e2 += dppf<DPP_X1>(e2);
            se += dppf<DPP_X2>(se); mr += dppf<DPP_X2>(mr); mi += dppf<DPP_X2>(mi); e2 += dppf<DPP_X2>(e2);
            se += dppf<DPP_M8>(se); mr += dppf<DPP_M8>(mr); mi += dppf<DPP_M8>(mi); e2 += dppf<DPP_M8>(e2);
            if (u == 0) {
                float inv = rcpf(se);
                float mxr = mr*inv, mxi = mi*inv;
                xc_[w][s] = (v2f){mxr, mxi};
                vx_[w][s] = e2*inv - (mxr*mxr + mxi*mxi);
            }
        }
        WSYNC();
        // setup: b_i = y_mf[i] - (g x)_i, A = I + g diag(var), C = g
        v2f xj = xc_[w][u];
        float vj = vx_[w][u];
        float tr = g_re*xj.x - g_im*xj.y;
        float ti = g_re*xj.y + g_im*xj.x;
        tr += dppf<DPP_X1>(tr); ti += dppf<DPP_X1>(ti);
        tr += dppf<DPP_X2>(tr); ti += dppf<DPP_X2>(ti);
        tr += dppf<DPP_M8>(tr); ti += dppf<DPP_M8>(ti);
        v2f ym = ymc_[w][s];
        float br_ = ym.x - tr, bi_ = ym.y - ti;
        float Ar = g_re*vj + ((s == u) ? 1.f : 0.f);
        float Ai = g_im*vj;
        float Cr = g_re, Ci = g_im;
        // inner unnormalized GJ on [A | b | C]: registers; pivot via v_readlane,
        // multiplier bcast via ds_swizzle (src=(L&0x38)|K), row bcast via bpermute.
        #define GJ_STEP(K) { \
            float pvr = rdlane(Ar, (K)*9), pvi = rdlane(Ai, (K)*9); \
            int rowsrc = ((K)<<3)|u; \
            float rAr = __shfl(Ar, rowsrc), rAi = __shfl(Ai, rowsrc); \
            float rCr = __shfl(Cr, rowsrc), rCi = __shfl(Ci, rowsrc); \
            float rbr = __shfl(br_, rowsrc), rbi = __shfl(bi_, rowsrc); \
            float cAr = swzf<(((K)<<5)|0x18)>(Ar), cAi = swzf<(((K)<<5)|0x18)>(Ai); \
            float id2 = rcpf(pvr*pvr + pvi*pvi); \
            float ipr2 = pvr*id2, ipi2 = -pvi*id2; \
            float mr2 = cAr*ipr2 - cAi*ipi2; \
            float mi2 = cAr*ipi2 + cAi*ipr2; \
            if (s == (K)) { mr2 = 0.f; mi2 = 0.f; } \
            Ar  -= mr2*rAr - mi2*rAi;  Ai  -= mr2*rAi + mi2*rAr; \
            Cr  -= mr2*rCr - mi2*rCi;  Ci  -= mr2*rCi + mi2*rCr; \
            br_ -= mr2*rbr - mi2*rbi;  bi_ -= mr2*rbi + mi2*rbr; }
        GJ_STEP(0) GJ_STEP(1) GJ_STEP(2) GJ_STEP(3)
        GJ_STEP(4) GJ_STEP(5) GJ_STEP(6) GJ_STEP(7)
        #undef GJ_STEP
        // extraction on diagonal lanes: z = (w + Cii*x)/mu, no_eff
        if (s == u) {
            float id3 = rcpf(Ar*Ar + Ai*Ai);
            float ipr3 = Ar*id3, ipi3 = -Ai*id3;
            float wr = br_*ipr3 - bi_*ipi3;
            float wi = br_*ipi3 + bi_*ipr3;
            float ccr = Cr*ipr3 - Ci*ipi3;
            float cci = Cr*ipi3 + Ci*ipr3;
            float mu = ccr;
            float im = rcpf(mu);
            float zr = (wr + ccr*xj.x - cci*xj.y) * im;
            float zi = (wi + ccr*xj.y + cci*xj.x) * im;
            xc_[w][s] = (v2f){zr, zi};
            ne_[w][s] = fmaxf(1.f - vx_[w][s]*mu, EPS_F) * im;
        }
        WSYNC();
        // demap (registers): exps for p=u (e0) and p=u+8 (e1)
        v2f xh = xc_[w][s];
        float idn = rcpf(ne_[w][s]);
        float dr0 = xh.x - pr, dr1 = xh.x + pr, di = xh.y - pi2;
        float e0 = l0 - (dr0*dr0 + di*di) * idn;
        float e1 = l1 - (dr1*dr1 + di*di) * idn;
        // max-log LLRs, fully in registers.
        // point index p bits (MSB..LSB): b3 = (e1 vs e0), b2 = u&4, b1 = u&2, b0 = u&1
        {
            float e = fmaxf(e0, e1);                       // collapse b3
            float h0 = e0;
            h0 = fmaxf(h0, dppf<DPP_X1>(h0)); h0 = fmaxf(h0, dppf<DPP_X2>(h0)); h0 = fmaxf(h0, dppf<DPP_M8>(h0));
            float h1 = e1;
            h1 = fmaxf(h1, dppf<DPP_X1>(h1)); h1 = fmaxf(h1, dppf<DPP_X2>(h1)); h1 = fmaxf(h1, dppf<DPP_M8>(h1));
            float L0 = h1 - h0;
            float s12 = fmaxf(e, dppf<DPP_X1>(e)); s12 = fmaxf(s12, dppf<DPP_X2>(s12));
            float s12p = swzf<SWX4>(s12);
            float L1 = (u & 4) ? (s12 - s12p) : (s12p - s12);
            float s14 = fmaxf(e, dppf<DPP_X1>(e)); s14 = fmaxf(s14, swzf<SWX4>(s14));
            float s14p = dppf<DPP_X2>(s14);
            float L2 = (u & 2) ? (s14 - s14p) : (s14p - s14);
            float s24 = fmaxf(e, dppf<DPP_X2>(e)); s24 = fmaxf(s24, swzf<SWX4>(s24));
            float s24p = dppf<DPP_X1>(s24);
            float L3 = (u & 1) ? (s24 - s24p) : (s24p - s24);
            if (u < 4) {
                float Lsel = (u == 0) ? L0 : (u == 1) ? L1 : (u == 2) ? L2 : L3;
                llrD_[w][s][u] = Lsel;
            }
        }
        WSYNC();
    }

    if (lane < 32) out[bs*32 + lane] = ((float*)llrD_[w])[lane] - llr_a_reg;
}

extern "C" void kernel_launch(void* const* d_in, const int* in_sizes, int n_in,
                              void* d_out, int out_size, void* d_ws, size_t ws_size,
                              hipStream_t stream) {
    const float* y_re  = (const float*)d_in[0];
    const float* y_im  = (const float*)d_in[1];
    const float* h_re  = (const float*)d_in[2];
    const float* h_im  = (const float*)d_in[3];
    const float* prior = (const float*)d_in[4];
    const float* s_re  = (const float*)d_in[5];
    const float* s_im  = (const float*)d_in[6];
    float* out = (float*)d_out;

    const int B = in_sizes[0] / 16;
    mmse_pic_kernel<<<dim3(B / 2), dim3(128), 0, stream>>>(
        y_re, y_im, h_re, h_im, prior, s_re, s_im, out);
}

// Round 11
// 240.880 us; speedup vs baseline: 1.0161x; 1.0161x over previous
//
#include <hip/hip_runtime.h>

// MMSE-PIC detector: B=32768, M=16, S=8, QAM16 Gray, 2 iterations.
// Round 11 = round 8 structure in 64-thread SINGLE-wave blocks.
// Why: with 2-wave blocks the compiler's LDS-derived occupancy (16wg cap ->
// 8 waves/EU) pins the VGPR budget at 64 and spills ~3.6KB/wave (R7-R10,
// WRITE_SIZE ~100MB; attrs and dead-pad tricks all failed to unpin).
// 1-wave blocks: 16wg/CU cap -> 16 waves/CU -> 4 waves/EU -> budget 128
// (proven spill-free in R3), and 16 waves/CU >= the ~14-wave issue
// saturation point, so the occupancy loss is cheap.
//  - b128 column-PAIR elimination (no j-guards; stale cols sloppily updated)
//  - DPP (quad_perm / row_half_mirror) butterflies on VALU pipe
//  - register-resident max-log LLR

#define EPS_F 1e-4f
#define INV_SQRT10 0.31622776601683794f
#define WSYNC() __builtin_amdgcn_wave_barrier()

typedef float v2f __attribute__((ext_vector_type(2)));

__device__ __forceinline__ float rcpf(float x) { return __builtin_amdgcn_rcpf(x); }
__device__ __forceinline__ float rsqf(float x) { return __builtin_amdgcn_rsqf(x); }
__device__ __forceinline__ float rdlane(float v, int l) {
    return __uint_as_float(__builtin_amdgcn_readlane(__float_as_uint(v), l));
}
template<int OFF>
__device__ __forceinline__ float swzf(float v) {
    return __uint_as_float(__builtin_amdgcn_ds_swizzle(__float_as_uint(v), OFF));
}
template<int CTRL>
__device__ __forceinline__ float dppf(float v) {
    return __int_as_float(__builtin_amdgcn_mov_dpp(__float_as_int(v), CTRL, 0xF, 0xF, true));
}
#define DPP_X1 0xB1   // quad_perm [1,0,3,2]  : lane ^ 1
#define DPP_X2 0x4E   // quad_perm [2,3,0,1]  : lane ^ 2
#define DPP_M8 0x141  // row_half_mirror      : lane ^ 7 within groups of 8
#define SWX4   0x101F // ds_swizzle           : lane ^ 4

__device__ __forceinline__ float pt_re(int p) {
    return (1.0f - 2.0f * (float)((p >> 3) & 1)) * (1.0f + 2.0f * (float)((p >> 1) & 1)) * INV_SQRT10;
}
__device__ __forceinline__ float pt_im(int p) {
    return (1.0f - 2.0f * (float)((p >> 2) & 1)) * (1.0f + 2.0f * (float)(p & 1)) * INV_SQRT10;
}

__global__ __launch_bounds__(64)
void mmse_pic_kernel(const float* __restrict__ y_re, const float* __restrict__ y_im,
                     const float* __restrict__ h_re, const float* __restrict__ h_im,
                     const float* __restrict__ prior,
                     const float* __restrict__ s_re, const float* __restrict__ s_im,
                     float* __restrict__ out)
{
    const int lane = threadIdx.x;
    const int b    = blockIdx.x;
    const size_t bs = (size_t)b;

    // cols: 0-15 = S, 16-23 = h, 24 = y, 25-27 pad (sloppy-write landing zone)
    __shared__ __align__(16) v2f Sc[16][28];
    __shared__ v2f   xc_[8];
    __shared__ v2f   ymc_[8];
    __shared__ float vx_[8], ne_[8];
    __shared__ float lsig[64];
    __shared__ float llrD_[8][4];

    // ---- load (vectorized, interleave re/im into float2) ----
    {
        const float4* pr4 = (const float4*)(s_re + bs * 256);
        const float4* pi4 = (const float4*)(s_im + bs * 256);
        float4 vr = pr4[lane], vi = pi4[lane];
        int r = lane >> 2, c0 = (lane & 3) << 2;
        Sc[r][c0+0] = (v2f){vr.x, vi.x};
        Sc[r][c0+1] = (v2f){vr.y, vi.y};
        Sc[r][c0+2] = (v2f){vr.z, vi.z};
        Sc[r][c0+3] = (v2f){vr.w, vi.w};
        if (lane < 32) {
            const float4* hr4 = (const float4*)(h_re + bs * 128);
            const float4* hi4 = (const float4*)(h_im + bs * 128);
            float4 hr = hr4[lane], hi = hi4[lane];
            int row = lane >> 1, col = 16 + ((lane & 1) << 2);
            Sc[row][col+0] = (v2f){hr.x, hi.x};
            Sc[row][col+1] = (v2f){hr.y, hi.y};
            Sc[row][col+2] = (v2f){hr.z, hi.z};
            Sc[row][col+3] = (v2f){hr.w, hi.w};
        }
        if (lane < 16) Sc[lane][24] = (v2f){y_re[bs*16+lane], y_im[bs*16+lane]};
        if (lane < 32) ((float*)llrD_)[lane] = prior[bs*32 + lane];
    }
    WSYNC();

    // ---- forward-only unnormalized elimination on [S | h y], column-pair b128 ----
    {
        const int r4 = lane >> 4;
        int jpr = lane & 15;
        const int jp = (jpr > 13) ? 13 : jpr;     // pairs 14,15 -> pad pair 13
        #pragma unroll
        for (int k = 0; k < 15; ++k) {
            float invd = rcpf(Sc[k][k].x);
            float4 rk = *(const float4*)&Sc[k][2*jp];
            const int p0 = k >> 2;
            #pragma unroll
            for (int p = 0; p < 4; ++p) {
                if (p < p0) continue;             // rows all finalized: skip
                int i = (p << 2) + r4;
                v2f aik = Sc[i][k];
                float mr = aik.x * invd, mi = aik.y * invd;
                if (p == p0) {                    // boundary block: protect rows i<=k
                    bool dead = (i <= k);
                    mr = dead ? 0.f : mr;
                    mi = dead ? 0.f : mi;
                }
                float4 a = *(float4*)&Sc[i][2*jp];
                a.x -= mr*rk.x - mi*rk.y;
                a.y -= mr*rk.y + mi*rk.x;
                a.z -= mr*rk.z - mi*rk.w;
                a.w -= mr*rk.w + mi*rk.z;
                *(float4*)&Sc[i][2*jp] = a;
            }
            WSYNC();
        }
    }
    // ---- scale RHS rows by rsqrt(d_m): W = D^-1/2 L^-1 [h|y] (= whitened) ----
    {
        int r2 = lane >> 2, c = lane & 3;
        float irs = rsqf(Sc[r2][r2].x);
        v2f v0 = Sc[r2][16 + c];
        Sc[r2][16 + c] = (v2f){v0.x*irs, v0.y*irs};
        v2f v1 = Sc[r2][20 + c];
        Sc[r2][20 + c] = (v2f){v1.x*irs, v1.y*irs};
        if (c == 0) {
            v2f v2 = Sc[r2][24];
            Sc[r2][24] = (v2f){v2.x*irs, v2.y*irs};
        }
    }
    WSYNC();

    // ---- Gram g[i][j] = (Wh^H Wh)[i][j] (1 entry/lane), y_mf = Wh^H Wy ----
    const int s = lane >> 3, u = lane & 7;
    float g_re = 0.f, g_im = 0.f, ym_r = 0.f, ym_i = 0.f;
    #pragma unroll
    for (int m = 0; m < 16; ++m) {
        v2f a  = Sc[m][16 + s];
        v2f x  = Sc[m][16 + u];
        v2f xy = Sc[m][24];
        g_re += a.x*x.x + a.y*x.y;      // conj(a)*x
        g_im += a.x*x.y - a.y*x.x;
        ym_r += a.x*xy.x + a.y*xy.y;
        ym_i += a.x*xy.y - a.y*xy.x;
    }
    if (u == 0) ymc_[s] = (v2f){ym_r, ym_i};
    WSYNC();

    const float pr = pt_re(u), pi2 = pt_im(u), pe = pr*pr + pi2*pi2;  // pt(u+8) = (-pr, pi2)
    float llr_a_reg = 0.f;

    for (int it = 0; it < 2; ++it) {
        // log-sigmoid table: one distinct value per lane
        {
            int ts = lane >> 3, tk = (lane >> 1) & 3, sg = lane & 1;
            float v = llrD_[ts][tk];
            float x = sg ? v : -v;
            lsig[lane] = fminf(x, 0.f) - __logf(1.0f + __expf(-fabsf(x)));
        }
        if (lane < 32) llr_a_reg = ((float*)llrD_)[lane];
        WSYNC();
        // symbol logits for p=u (l0) and p=u+8 (l1), in registers
        int base = s << 3;
        float lc = lsig[base | 2 | ((u >> 2) & 1)]
                 + lsig[base | 4 | ((u >> 1) & 1)]
                 + lsig[base | 6 | (u & 1)];
        float l0 = lc + lsig[base];
        float l1 = lc + lsig[base | 1];
        // moments: DPP-butterfly over the 8 lanes of stream s
        {
            float mx = fmaxf(l0, l1);
            mx = fmaxf(mx, dppf<DPP_X1>(mx));
            mx = fmaxf(mx, dppf<DPP_X2>(mx));
            mx = fmaxf(mx, dppf<DPP_M8>(mx));
            float w0 = __expf(l0 - mx), w1 = __expf(l1 - mx);
            float a = w0 + w1, dw = w0 - w1;
            float se = a, mr = dw * pr, mi = a * pi2, e2 = a * pe;
            se += dppf<DPP_X1>(se); mr += dppf<DPP_X1>(mr); mi += dppf<DPP_X1>(mi); e2 += dppf<DPP_X1>(e2);
            se += dppf<DPP_X2>(se); mr += dppf<DPP_X2>(mr); mi += dppf<DPP_X2>(mi); e2 += dppf<DPP_X2>(e2);
            se += dppf<DPP_M8>(se); mr += dppf<DPP_M8>(mr); mi += dppf<DPP_M8>(mi); e2 += dppf<DPP_M8>(e2);
            if (u == 0) {
                float inv = rcpf(se);
                float mxr = mr*inv, mxi = mi*inv;
                xc_[s] = (v2f){mxr, mxi};
                vx_[s] = e2*inv - (mxr*mxr + mxi*mxi);
            }
        }
        WSYNC();
        // setup: b_i = y_mf[i] - (g x)_i, A = I + g diag(var), C = g
        v2f xj = xc_[u];
        float vj = vx_[u];
        float tr = g_re*xj.x - g_im*xj.y;
        float ti = g_re*xj.y + g_im*xj.x;
        tr += dppf<DPP_X1>(tr); ti += dppf<DPP_X1>(ti);
        tr += dppf<DPP_X2>(tr); ti += dppf<DPP_X2>(ti);
        tr += dppf<DPP_M8>(tr); ti += dppf<DPP_M8>(ti);
        v2f ym = ymc_[s];
        float br_ = ym.x - tr, bi_ = ym.y - ti;
        float Ar = g_re*vj + ((s == u) ? 1.f : 0.f);
        float Ai = g_im*vj;
        float Cr = g_re, Ci = g_im;
        // inner unnormalized GJ on [A | b | C]: registers; pivot via v_readlane,
        // multiplier bcast via ds_swizzle (src=(L&0x38)|K), row bcast via bpermute.
        #define GJ_STEP(K) { \
            float pvr = rdlane(Ar, (K)*9), pvi = rdlane(Ai, (K)*9); \
            int rowsrc = ((K)<<3)|u; \
            float rAr = __shfl(Ar, rowsrc), rAi = __shfl(Ai, rowsrc); \
            float rCr = __shfl(Cr, rowsrc), rCi = __shfl(Ci, rowsrc); \
            float rbr = __shfl(br_, rowsrc), rbi = __shfl(bi_, rowsrc); \
            float cAr = swzf<(((K)<<5)|0x18)>(Ar), cAi = swzf<(((K)<<5)|0x18)>(Ai); \
            float id2 = rcpf(pvr*pvr + pvi*pvi); \
            float ipr2 = pvr*id2, ipi2 = -pvi*id2; \
            float mr2 = cAr*ipr2 - cAi*ipi2; \
            float mi2 = cAr*ipi2 + cAi*ipr2; \
            if (s == (K)) { mr2 = 0.f; mi2 = 0.f; } \
            Ar  -= mr2*rAr - mi2*rAi;  Ai  -= mr2*rAi + mi2*rAr; \
            Cr  -= mr2*rCr - mi2*rCi;  Ci  -= mr2*rCi + mi2*rCr; \
            br_ -= mr2*rbr - mi2*rbi;  bi_ -= mr2*rbi + mi2*rbr; }
        GJ_STEP(0) GJ_STEP(1) GJ_STEP(2) GJ_STEP(3)
        GJ_STEP(4) GJ_STEP(5) GJ_STEP(6) GJ_STEP(7)
        #undef GJ_STEP
        // extraction on diagonal lanes: z = (w + Cii*x)/mu, no_eff
        if (s == u) {
            float id3 = rcpf(Ar*Ar + Ai*Ai);
            float ipr3 = Ar*id3, ipi3 = -Ai*id3;
            float wr = br_*ipr3 - bi_*ipi3;
            float wi = br_*ipi3 + bi_*ipr3;
            float ccr = Cr*ipr3 - Ci*ipi3;
            float cci = Cr*ipi3 + Ci*ipr3;
            float mu = ccr;
            float im = rcpf(mu);
            float zr = (wr + ccr*xj.x - cci*xj.y) * im;
            float zi = (wi + ccr*xj.y + cci*xj.x) * im;
            xc_[s] = (v2f){zr, zi};
            ne_[s] = fmaxf(1.f - vx_[s]*mu, EPS_F) * im;
        }
        WSYNC();
        // demap (registers): exps for p=u (e0) and p=u+8 (e1)
        v2f xh = xc_[s];
        float idn = rcpf(ne_[s]);
        float dr0 = xh.x - pr, dr1 = xh.x + pr, di = xh.y - pi2;
        float e0 = l0 - (dr0*dr0 + di*di) * idn;
        float e1 = l1 - (dr1*dr1 + di*di) * idn;
        // max-log LLRs, fully in registers.
        // point index p bits (MSB..LSB): b3 = (e1 vs e0), b2 = u&4, b1 = u&2, b0 = u&1
        {
            float e = fmaxf(e0, e1);                       // collapse b3
            float h0 = e0;
            h0 = fmaxf(h0, dppf<DPP_X1>(h0)); h0 = fmaxf(h0, dppf<DPP_X2>(h0)); h0 = fmaxf(h0, dppf<DPP_M8>(h0));
            float h1 = e1;
            h1 = fmaxf(h1, dppf<DPP_X1>(h1)); h1 = fmaxf(h1, dppf<DPP_X2>(h1)); h1 = fmaxf(h1, dppf<DPP_M8>(h1));
            float L0 = h1 - h0;
            float s12 = fmaxf(e, dppf<DPP_X1>(e)); s12 = fmaxf(s12, dppf<DPP_X2>(s12));
            float s12p = swzf<SWX4>(s12);
            float L1 = (u & 4) ? (s12 - s12p) : (s12p - s12);
            float s14 = fmaxf(e, dppf<DPP_X1>(e)); s14 = fmaxf(s14, swzf<SWX4>(s14));
            float s14p = dppf<DPP_X2>(s14);
            float L2 = (u & 2) ? (s14 - s14p) : (s14p - s14);
            float s24 = fmaxf(e, dppf<DPP_X2>(e)); s24 = fmaxf(s24, swzf<SWX4>(s24));
            float s24p = dppf<DPP_X1>(s24);
            float L3 = (u & 1) ? (s24 - s24p) : (s24p - s24);
            if (u < 4) {
                float Lsel = (u == 0) ? L0 : (u == 1) ? L1 : (u == 2) ? L2 : L3;
                llrD_[s][u] = Lsel;
            }
        }
        WSYNC();
    }

    if (lane < 32) out[bs*32 + lane] = ((float*)llrD_)[lane] - llr_a_reg;
}

extern "C" void kernel_launch(void* const* d_in, const int* in_sizes, int n_in,
                              void* d_out, int out_size, void* d_ws, size_t ws_size,
                              hipStream_t stream) {
    const float* y_re  = (const float*)d_in[0];
    const float* y_im  = (const float*)d_in[1];
    const float* h_re  = (const float*)d_in[2];
    const float* h_im  = (const float*)d_in[3];
    const float* prior = (const float*)d_in[4];
    const float* s_re  = (const float*)d_in[5];
    const float* s_im  = (const float*)d_in[6];
    float* out = (float*)d_out;

    const int B = in_sizes[0] / 16;
    mmse_pic_kernel<<<dim3(B), dim3(64), 0, stream>>>(
        y_re, y_im, h_re, h_im, prior, s_re, s_im, out);
}